// Round 3
// baseline (194.395 us; speedup 1.0000x reference)
//
#include <hip/hip_runtime.h>
#include <stdint.h>

typedef unsigned short u16;
typedef unsigned int u32;
typedef __attribute__((ext_vector_type(8))) __bf16 bf16x8;
typedef __attribute__((ext_vector_type(4))) float f32x4;

#define N_IMG 64
#define C_IN  64
#define HW_IN 3136   // 56*56
#define W_IN  56
#define C_OUT 128
#define OH    54
#define OW    54
#define SPI   2916   // 54*54
#define KTOT  576    // C_IN*9
#define M_TOTAL (N_IMG*SPI)   // 186624 = 128 * 1458

typedef __attribute__((address_space(3))) unsigned int lds_uint;
typedef __attribute__((address_space(1))) unsigned int gbl_uint;

__device__ __forceinline__ void load16_to_lds(const u16* g, u16* l) {
  // lane i of the wave writes LDS base + i*16 bytes; g is per-lane.
  __builtin_amdgcn_global_load_lds((const gbl_uint*)g, (lds_uint*)l, 16, 0, 0);
}

__device__ inline u16 f32_bf16_rne(float f) {
  unsigned u = __float_as_uint(f);
  u = (u + 0x7FFFu + ((u >> 16) & 1u)) >> 16;
  return (u16)u;
}

// One launch does both conversions.
//  blockIdx.x < 49 : x NCHW fp32 -> xt NHWC bf16 (clip+trunc; ints exact in bf16)
//  blockIdx.x == 49: w OIHW fp32 -> wtT[co][(kh*3+kw)*64+ci] bf16
__global__ __launch_bounds__(256) void convert_xw(const float* __restrict__ x,
                                                  const float* __restrict__ w,
                                                  u16* __restrict__ xt,
                                                  u16* __restrict__ wtT) {
  if (blockIdx.x == 49) {
    int o = blockIdx.y * 256 + threadIdx.x;    // 16384 threads for 73728 elems
    #pragma unroll
    for (int it = 0; it < 5; it++) {
      int oo = o + it * 16384;
      if (oo < C_OUT * KTOT) {
        int co = oo / KTOT;
        int k  = oo - co * KTOT;
        int t2 = k >> 6, ci = k & 63;
        wtT[oo] = f32_bf16_rne(w[co * KTOT + ci * 9 + t2]);
      }
    }
    return;
  }
  __shared__ u16 tile[64][65];   // pad 65 (odd) -> conflict-free both phases
  int t  = threadIdx.x;
  int tx = t & 63, ty = t >> 6;
  int n  = blockIdx.y;
  int s0 = blockIdx.x * 64;
  const float* xp = x + (size_t)n * C_IN * HW_IN + s0;
  #pragma unroll
  for (int i = ty; i < 64; i += 4) {           // i = ci row; 256 B coalesced read
    float v = xp[i * HW_IN + tx];
    v = fminf(fmaxf(v, -128.f), 127.f);
    v = truncf(v);                             // == (float)(int)v here
    tile[i][tx] = (u16)(__float_as_uint(v) >> 16);  // exact: ints |v|<=128 in bf16
  }
  __syncthreads();
  u32* op = (u32*)(xt + (size_t)n * HW_IN * C_IN) + (size_t)s0 * 32;
  #pragma unroll
  for (int j = 0; j < 8; j++) {                // packed u32 writes: 2x128 B per wave
    int sp = j * 8 + ty * 2 + (tx >> 5);
    int cp = tx & 31;
    u32 lo = tile[2 * cp][sp];
    u32 hi = tile[2 * cp + 1][sp];
    op[sp * 32 + cp] = lo | (hi << 16);
  }
}

// Implicit GEMM: 128 spatial x 128 cout block, BK=64 (one 3x3 tap), 9 chunks.
// Double-buffered LDS (64 KB), ONE barrier per chunk, prefetch issued right
// after the barrier so the next barrier's vmcnt drain waits only residual
// latency. XOR-16B-group swizzle on the global side of the DMA.
__global__ __launch_bounds__(256) void conv_gemm(
    const u16* __restrict__ xt, const u16* __restrict__ wtT,
    const float* __restrict__ bias, float* __restrict__ y)
{
  __shared__ u16 sP[2][8192];   // pixels  [buf][row*64 + swizzled group]
  __shared__ u16 sW[2][8192];   // weights

  int tid  = threadIdx.x;
  int wv   = tid >> 6;
  int lane = tid & 63;
  int ln   = lane & 15;
  int q    = lane >> 4;
  int wy   = wv >> 1;            // cout half
  int wx   = wv & 1;             // spatial half

  int blk_sp0 = blockIdx.x * 128;

  // staging addresses: lane i -> row i>>3, 16B-group i&7, swizzle cg^row8
  int r8 = lane >> 3;
  int cg = lane & 7;
  int scol = (cg ^ r8) * 8;

  int pix_off[4], wt_off[4];
  #pragma unroll
  for (int j = 0; j < 4; j++) {
    int srow = wv * 32 + j * 8 + r8;
    int p   = blk_sp0 + srow;
    int img = p / SPI;  int rem = p - img * SPI;
    int oh  = rem / OW; int ow  = rem - oh * OW;
    pix_off[j] = (img * HW_IN + oh * W_IN + ow) * C_IN + scol;
    wt_off[j]  = srow * KTOT + scol;
  }

  f32x4 acc[4][4];
  #pragma unroll
  for (int mt = 0; mt < 4; mt++)
    #pragma unroll
    for (int nt = 0; nt < 4; nt++)
      acc[mt][nt] = (f32x4){0.f, 0.f, 0.f, 0.f};

  int wrow[4], prow[4];
  #pragma unroll
  for (int i = 0; i < 4; i++) {
    wrow[i] = (wy * 64 + i * 16 + ln) * 64;
    prow[i] = (wx * 64 + i * 16 + ln) * 64;
  }
  int l7 = ln & 7;

#define STAGE(KC, BUF) do {                                                   \
    int xoff_ = (((KC) / 3) * W_IN + ((KC) % 3)) * C_IN;                      \
    _Pragma("unroll")                                                         \
    for (int j_ = 0; j_ < 4; j_++)                                            \
      load16_to_lds(xt + pix_off[j_] + xoff_,                                 \
                    &sP[BUF][(wv * 32 + j_ * 8) * 64]);                       \
    _Pragma("unroll")                                                         \
    for (int j_ = 0; j_ < 4; j_++)                                            \
      load16_to_lds(wtT + wt_off[j_] + (KC) * 64,                             \
                    &sW[BUF][(wv * 32 + j_ * 8) * 64]);                       \
  } while (0)

  STAGE(0, 0);

  #pragma unroll
  for (int kc = 0; kc < 9; kc++) {
    int rb = kc & 1;
    __syncthreads();               // drains stage(kc); protects buf rb^1
    if (kc < 8) STAGE(kc + 1, rb ^ 1);   // prefetch with ~compute-time head start

    #pragma unroll
    for (int s = 0; s < 2; s++) {
      int pg = ((s * 4 + q) ^ l7) * 8;   // unswizzled physical group
      bf16x8 wf[4], pf[4];
      #pragma unroll
      for (int mt = 0; mt < 4; mt++)
        wf[mt] = *(const bf16x8*)(&sW[rb][0] + wrow[mt] + pg);
      #pragma unroll
      for (int nt = 0; nt < 4; nt++)
        pf[nt] = *(const bf16x8*)(&sP[rb][0] + prow[nt] + pg);
      #pragma unroll
      for (int mt = 0; mt < 4; mt++)
        #pragma unroll
        for (int nt = 0; nt < 4; nt++)
          acc[mt][nt] = __builtin_amdgcn_mfma_f32_16x16x32_bf16(
              wf[mt], pf[nt], acc[mt][nt], 0, 0, 0);
    }
  }
#undef STAGE

  // Epilogue: LDS-bounce per wave (private 16x66 fp32 slice, no barrier between
  // mt slices) -> 64-lane dense 256 B stores, fixing half-line write traffic.
  __syncthreads();                 // before reusing sP as scratch
  float* wbuf = ((float*)sP) + wv * (16 * 66);
  int p   = blk_sp0 + wx * 64 + lane;
  int img = p / SPI;  int rem = p - img * SPI;
  size_t ybase = (size_t)img * C_OUT * SPI + rem;

  #pragma unroll
  for (int mt = 0; mt < 4; mt++) {
    #pragma unroll
    for (int nt = 0; nt < 4; nt++)
      #pragma unroll
      for (int r = 0; r < 4; r++)
        wbuf[(q * 4 + r) * 66 + nt * 16 + ln] = acc[mt][nt][r];
    int co0 = wy * 64 + mt * 16;
    #pragma unroll
    for (int c = 0; c < 16; c++) {
      float v = wbuf[c * 66 + lane] + bias[co0 + c];
      y[ybase + (size_t)(co0 + c) * SPI] = v;
    }
  }
}

extern "C" void kernel_launch(void* const* d_in, const int* in_sizes, int n_in,
                              void* d_out, int out_size, void* d_ws, size_t ws_size,
                              hipStream_t stream) {
  const float* x    = (const float*)d_in[0];
  const float* w    = (const float*)d_in[1];
  const float* bias = (const float*)d_in[2];
  float* y = (float*)d_out;

  u16* wtT = (u16*)d_ws;
  u16* xt  = (u16*)((char*)d_ws + (size_t)C_OUT * KTOT * sizeof(u16)); // +147456 B

  hipLaunchKernelGGL(convert_xw, dim3(50, 64), dim3(256), 0, stream, x, w, xt, wtT);
  hipLaunchKernelGGL(conv_gemm, dim3(M_TOTAL / 128), dim3(256), 0, stream,
                     xt, wtT, bias, y);
}